// Round 1
// baseline (366.906 us; speedup 1.0000x reference)
//
#include <hip/hip_runtime.h>

// ODEFunc: continuous normalizing flow dynamics.
// Inputs (fp32): t(1, unused), z_and_logp(B,3), W1(64,2), b1(64),
//                W2(64,64), b2(64), W3(2,64), b3(2)
// Output (fp32): (B,3) = [f(z)_0, f(z)_1, -trace(J)]
//
// One thread per row. h1/u/v live in 192 VGPRs (j fully unrolled).
// W2 in LDS, read wave-uniform (broadcast). Compute-bound on fp32 VALU.

__global__ __launch_bounds__(256, 2)
void odefunc_kernel(const float* __restrict__ zin,
                    const float* __restrict__ W1, const float* __restrict__ b1,
                    const float* __restrict__ W2, const float* __restrict__ b2,
                    const float* __restrict__ W3, const float* __restrict__ b3,
                    float* __restrict__ out, int B)
{
    __shared__ float sW2[64 * 64];   // 16 KiB
    __shared__ float sW1[128];
    __shared__ float sb1[64];
    __shared__ float sb2[64];
    __shared__ float sW3[128];
    __shared__ float sb3[2];

    // Cooperative weight staging (once per block).
    {
        const float4* src = (const float4*)W2;
        float4* dst = (float4*)sW2;
        for (int i = threadIdx.x; i < 1024; i += blockDim.x) dst[i] = src[i];
        int t = threadIdx.x;
        if (t < 128) sW1[t] = W1[t];
        if (t >= 128 && t < 256) sW3[t - 128] = W3[t - 128];
        if (t < 64) { sb1[t] = b1[t]; sb2[t] = b2[t]; }
        if (t == 0) { sb3[0] = b3[0]; sb3[1] = b3[1]; }
    }
    __syncthreads();

    int r = blockIdx.x * blockDim.x + threadIdx.x;
    if (r >= B) return;

    float z0 = zin[3 * r + 0];
    float z1 = zin[3 * r + 1];

    // ---- Layer 1 + ELU + tangent seeds (all in registers) ----
    float h1[64], uu[64], vv[64];
#pragma unroll
    for (int j = 0; j < 64; ++j) {
        float w0 = sW1[2 * j + 0];
        float w1 = sW1[2 * j + 1];
        float a = fmaf(w0, z0, fmaf(w1, z1, sb1[j]));
        float ex = __expf(fminf(a, 0.f));   // clamp: avoid inf for a>0
        bool pos = a > 0.f;
        float h = pos ? a : (ex - 1.f);     // elu
        float g = pos ? 1.f : ex;           // elu'
        h1[j] = h;
        uu[j] = g * w0;                     // d(h1_j)/dz0
        vv[j] = g * w1;                     // d(h1_j)/dz1
    }

    // ---- Layer 2 (3 matvecs vs W2) + ELU + layer 3 folded ----
    float out0 = sb3[0], out1 = sb3[1], tr = 0.f;
#pragma unroll 2
    for (int k = 0; k < 64; ++k) {
        const float4* wrow = (const float4*)(&sW2[k * 64]);
        float acc = sb2[k];
        float d0 = 0.f, d1 = 0.f;
#pragma unroll
        for (int j4 = 0; j4 < 16; ++j4) {
            float4 w = wrow[j4];            // wave-uniform -> LDS broadcast
            int j = 4 * j4;
            acc = fmaf(w.x, h1[j + 0], acc);
            d0  = fmaf(w.x, uu[j + 0], d0);
            d1  = fmaf(w.x, vv[j + 0], d1);
            acc = fmaf(w.y, h1[j + 1], acc);
            d0  = fmaf(w.y, uu[j + 1], d0);
            d1  = fmaf(w.y, vv[j + 1], d1);
            acc = fmaf(w.z, h1[j + 2], acc);
            d0  = fmaf(w.z, uu[j + 2], d0);
            d1  = fmaf(w.z, vv[j + 2], d1);
            acc = fmaf(w.w, h1[j + 3], acc);
            d0  = fmaf(w.w, uu[j + 3], d0);
            d1  = fmaf(w.w, vv[j + 3], d1);
        }
        float ex = __expf(fminf(acc, 0.f));
        bool pos = acc > 0.f;
        float h = pos ? acc : (ex - 1.f);
        float g = pos ? 1.f : ex;
        float w30 = sW3[k];        // W3[0,k]
        float w31 = sW3[64 + k];   // W3[1,k]
        out0 = fmaf(w30, h, out0);
        out1 = fmaf(w31, h, out1);
        tr = fmaf(w30, g * d0, fmaf(w31, g * d1, tr));
    }

    out[3 * r + 0] = out0;
    out[3 * r + 1] = out1;
    out[3 * r + 2] = -tr;
}

extern "C" void kernel_launch(void* const* d_in, const int* in_sizes, int n_in,
                              void* d_out, int out_size, void* d_ws, size_t ws_size,
                              hipStream_t stream) {
    // d_in: 0=t(unused) 1=z_and_logp 2=W1 3=b1 4=W2 5=b2 6=W3 7=b3
    const float* zin = (const float*)d_in[1];
    const float* W1  = (const float*)d_in[2];
    const float* b1  = (const float*)d_in[3];
    const float* W2  = (const float*)d_in[4];
    const float* b2  = (const float*)d_in[5];
    const float* W3  = (const float*)d_in[6];
    const float* b3  = (const float*)d_in[7];
    float* out = (float*)d_out;

    int B = in_sizes[1] / 3;
    int grid = (B + 255) / 256;
    odefunc_kernel<<<grid, 256, 0, stream>>>(zin, W1, b1, W2, b2, W3, b3, out, B);
}